// Round 2
// baseline (303.698 us; speedup 1.0000x reference)
//
#include <hip/hip_runtime.h>
#include <math.h>

#define DT   0.1f
#define HDT  0.005f
#define T_HIST 20
#define LEN_PRED 30

typedef __attribute__((ext_vector_type(8))) short bfrag8;   // 8 bf16 = 4 VGPRs
typedef __attribute__((ext_vector_type(4))) short short4v;  // 8 bytes
typedef __attribute__((ext_vector_type(4))) float f32x4;
typedef __attribute__((ext_vector_type(2))) float f32x2;

static __device__ __forceinline__ unsigned short f2bf(float x) {
    union { float f; unsigned int u; } v; v.f = x;
    unsigned int r = v.u + 0x7fffu + ((v.u >> 16) & 1u);   // RNE
    return (unsigned short)(r >> 16);
}

// ---------------- persistent kernel: 16 elems / 4-wave block ----------------
// wave v owns gate v (rows v*32..v*32+31 of the 128-gate stack) for MFMA;
// elementwise LSTM math is redistributed across all 256 threads (2 outputs each).
__launch_bounds__(256, 1)
__global__ void kalman_lstm_kernel(const float* __restrict__ hist,
                                   const float* __restrict__ max_ax, const float* __restrict__ max_ay,
                                   const float* __restrict__ vstd, const float* __restrict__ astd,
                                   const float* __restrict__ Rx_, const float* __restrict__ Ry_,
                                   const float* __restrict__ Gx, const float* __restrict__ Gy,
                                   const float* __restrict__ Win_W, const float* __restrict__ Win_b,
                                   const float* __restrict__ eWih, const float* __restrict__ eWhh,
                                   const float* __restrict__ ebih, const float* __restrict__ ebhh,
                                   const float* __restrict__ dWih, const float* __restrict__ dWhh,
                                   const float* __restrict__ dbih, const float* __restrict__ dbhh,
                                   const float* __restrict__ Wout_W, const float* __restrict__ Wout_b,
                                   float* __restrict__ out)
{
    __shared__ __align__(16) unsigned short xp[16][40];         // XP bf16, cols 24..39 zero
    __shared__ __align__(16) unsigned short xin[4][16][40];     // layer inputs (x0, c0, c1, c2)
    __shared__ __align__(16) unsigned short hbuf[2][3][16][40]; // double-buffered h
    __shared__ __align__(16) float bias_lds[2][3][128];         // combined bih+bhh
    __shared__ __align__(16) float pre[4][32][18];              // fp32 pre-acts [gate][feat][elem+pad]

    const int tid  = threadIdx.x;
    const int wv   = tid >> 6;        // wave 0..3 == gate id for MFMA; 0/1 also Kalman x/y
    const int lane = tid & 63;
    const int q    = lane >> 4;
    const int m    = lane & 15;       // elem col (B/D), row-in-tile (A)
    const int base = blockIdx.x * 16;
    const int b_elem = base + m;

    // ---- load this wave's weight frags directly from global (L2-hot) ----
    // A-frag layout: lane(q,m) holds A[row=tile*16+m][k=q*8+j]
    bfrag8 fragL[2][3][2][2];         // [phase][layer][tile(0:feat0-15,1:feat16-31)][0=Wih,1=Whh]
#pragma unroll
    for (int ph = 0; ph < 2; ++ph)
#pragma unroll
        for (int l = 0; l < 3; ++l)
#pragma unroll
            for (int t = 0; t < 2; ++t)
#pragma unroll
                for (int c = 0; c < 2; ++c) {
                    const float* W = (c == 0) ? (ph ? dWih : eWih) : (ph ? dWhh : eWhh);
                    int row = wv * 32 + t * 16 + m;
                    union { bfrag8 v; unsigned short s[8]; } u;
#pragma unroll
                    for (int j = 0; j < 8; ++j)
                        u.s[j] = f2bf(W[l * 4096 + row * 32 + q * 8 + j]);
                    fragL[ph][l][t][c] = u.v;
                }

    // Win / Wout frags + biases (waves 0,1 only use these)
    bfrag8 winF = {}, woutF = {};
    f32x4 winB = {0.f, 0.f, 0.f, 0.f}, woutB = {0.f, 0.f, 0.f, 0.f};
    if (wv < 2) {
        union { bfrag8 v; unsigned short s[8]; } u;
#pragma unroll
        for (int j = 0; j < 8; ++j) {
            int k = q * 8 + j;
            u.s[j] = (k < 24) ? f2bf(Win_W[(wv * 16 + m) * 24 + k]) : 0;
        }
        winF = u.v;
#pragma unroll
        for (int j = 0; j < 8; ++j)
            u.s[j] = (m < 4) ? f2bf(Wout_W[m * 32 + q * 8 + j]) : 0;
        woutF = u.v;
#pragma unroll
        for (int r = 0; r < 4; ++r) winB[r] = Win_b[wv * 16 + q * 4 + r];
#pragma unroll
        for (int r = 0; r < 4; ++r) woutB[r] = Wout_b[r];
    }

    // ---- cooperative LDS init ----
    for (int idx = tid; idx < 768; idx += 256) {
        int ph = idx / 384, rem = idx - ph * 384;
        int l = rem >> 7, row = rem & 127;
        const float* bi = ph ? dbih : ebih;
        const float* bh = ph ? dbhh : ebhh;
        ((float*)bias_lds)[idx] = bi[l * 128 + row] + bh[l * 128 + row];
    }
    for (int idx = tid; idx < 16 * 40; idx += 256) (&xp[0][0])[idx] = 0;
    for (int idx = tid; idx < 4 * 16 * 40; idx += 256) (&xin[0][0][0])[idx] = 0;
    for (int idx = tid; idx < 2 * 3 * 16 * 40; idx += 256) (&hbuf[0][0][0][0])[idx] = 0;

    // ---- Kalman state (waves 0,1 = channels x,y; lanes q==0 authoritative) ----
    float g0 = 0.f, g1 = 0.f, g2 = 0.f, ge0 = 0.f, ge1 = 0.f, ge2 = 0.f;
    float Rch = 0.f, X0 = 0.f, X1 = 0.f, X2 = 0.f;
    float P00 = 0.f, P01 = 0.f, P02 = 0.f, P11 = 0.f, P12 = 0.f, P22 = 0.f;
    if (wv < 2) {
        const float rx = Rx_[0] * Rx_[0], ry = Ry_[0] * Ry_[0];
        Rch = wv ? ry : rx;
        if (wv == 0) { g0 = Gx[0]; g1 = Gx[1]; g2 = Gx[2]; float s = max_ax[0]; ge0 = g0*s; ge1 = g1*s; ge2 = g2*s; }
        else         { g0 = Gy[0]; g1 = Gy[1]; g2 = Gy[2]; float s = max_ay[0]; ge0 = g0*s; ge1 = g1*s; ge2 = g2*s; }
        X0 = hist[b_elem * (T_HIST * 2) + wv];
        P00 = Rch; P11 = vstd[0] * vstd[0]; P22 = astd[0] * astd[0];
    }

    // elementwise ownership: thread handles outputs (feat, e0) and (feat, e0+1)
    const int feat = tid >> 3;
    const int e0 = (tid & 7) * 2;
    float creg[3][2];
#pragma unroll
    for (int l = 0; l < 3; ++l) { creg[l][0] = 0.f; creg[l][1] = 0.f; }

    auto write_xp = [&]() {
        if (wv < 2 && q == 0) {
            int o = wv * 3;
            xp[m][o + 0] = f2bf(X0); xp[m][o + 1] = f2bf(X1); xp[m][o + 2] = f2bf(X2);
            int pb = 6 + wv * 9;
            xp[m][pb + 0] = f2bf(P00); xp[m][pb + 1] = f2bf(P01); xp[m][pb + 2] = f2bf(P02);
            xp[m][pb + 3] = f2bf(P01); xp[m][pb + 4] = f2bf(P11); xp[m][pb + 5] = f2bf(P12);
            xp[m][pb + 6] = f2bf(P02); xp[m][pb + 7] = f2bf(P12); xp[m][pb + 8] = f2bf(P22);
        }
    };

    auto sig = [](float z) { return __builtin_amdgcn_rcpf(1.f + __expf(-z)); };
    auto th  = [](float z) { return fmaf(-2.f, __builtin_amdgcn_rcpf(__expf(2.f * z) + 1.f), 1.f); };

    auto kpred = [&](float Q00, float Q01, float Q02, float Q11, float Q12, float Q22) {
        X0 = X0 + DT * X1 + HDT * X2;
        X1 = X1 + DT * X2;
        float M00 = P00 + DT * P01 + HDT * P02;
        float M01 = P01 + DT * P11 + HDT * P12;
        float M02 = P02 + DT * P12 + HDT * P22;
        float M11 = P11 + DT * P12;
        float M12 = P12 + DT * P22;
        float M22 = P22;
        P00 = M00 + DT * M01 + HDT * M02 + Q00;
        P01 = M01 + DT * M02 + Q01;
        P02 = M02 + Q02;
        P11 = M11 + DT * M12 + Q11;
        P12 = M12 + Q12;
        P22 = M22 + Q22;
    };

    const f32x4 zero4 = {0.f, 0.f, 0.f, 0.f};

    // one LSTM-stack step; ph literal at call site so fragL[ph] folds to regs
    auto stack = [&](int ph, int p) {
        if (wv < 2) {   // Win: x0 = tanh(XP @ Win^T + b); wave wv covers feats wv*16..+15
            bfrag8 bxp = *(const bfrag8*)&xp[m][q * 8];
            f32x4 aw = __builtin_amdgcn_mfma_f32_16x16x32_bf16(winF, bxp, zero4, 0, 0, 0);
            union { short4v v; unsigned short s[4]; } u;
#pragma unroll
            for (int r = 0; r < 4; ++r) u.s[r] = f2bf(th(aw[r] + winB[r]));
            *(short4v*)&xin[0][m][wv * 16 + q * 4] = u.v;
        }
        __syncthreads();
#pragma unroll
        for (int l = 0; l < 3; ++l) {
            // MFMA: wave wv computes gate wv's 32 features x 16 elems
            bfrag8 bx = *(const bfrag8*)&xin[l][m][q * 8];
            bfrag8 bh = *(const bfrag8*)&hbuf[p][l][m][q * 8];
            f32x4 a0 = __builtin_amdgcn_mfma_f32_16x16x32_bf16(fragL[ph][l][0][0], bx, zero4, 0, 0, 0);
            a0        = __builtin_amdgcn_mfma_f32_16x16x32_bf16(fragL[ph][l][0][1], bh, a0, 0, 0, 0);
            f32x4 a1 = __builtin_amdgcn_mfma_f32_16x16x32_bf16(fragL[ph][l][1][0], bx, zero4, 0, 0, 0);
            a1        = __builtin_amdgcn_mfma_f32_16x16x32_bf16(fragL[ph][l][1][1], bh, a1, 0, 0, 0);
            f32x4 bb0 = *(const f32x4*)&bias_lds[ph][l][wv * 32 + q * 4];
            f32x4 bb1 = *(const f32x4*)&bias_lds[ph][l][wv * 32 + 16 + q * 4];
#pragma unroll
            for (int r = 0; r < 4; ++r) pre[wv][q * 4 + r][m] = a0[r] + bb0[r];
#pragma unroll
            for (int r = 0; r < 4; ++r) pre[wv][16 + q * 4 + r][m] = a1[r] + bb1[r];
            __syncthreads();
            // elementwise: 512 c-updates spread over 256 threads (2 each)
            f32x2 gi = *(const f32x2*)&pre[0][feat][e0];
            f32x2 gf = *(const f32x2*)&pre[1][feat][e0];
            f32x2 gg = *(const f32x2*)&pre[2][feat][e0];
            f32x2 go = *(const f32x2*)&pre[3][feat][e0];
#pragma unroll
            for (int j = 0; j < 2; ++j) {
                float iv = sig(gi[j]);
                float fv = sig(gf[j]);
                float gvv = th(gg[j]);
                float ov = sig(go[j]);
                float cn = fmaf(fv, creg[l][j], iv * gvv);
                float hn = ov * th(cn);
                creg[l][j] = cn;
                xin[l + 1][e0 + j][feat] = f2bf(cn);
                hbuf[p ^ 1][l][e0 + j][feat] = f2bf(hn);
            }
            __syncthreads();
        }
    };

    __syncthreads();     // LDS init visible
    write_xp();
    int parity = 0;

    // ---------------- encoder: 19 steps ----------------
    for (int t = 0; t < T_HIST - 1; ++t) {
        __syncthreads();                                  // xp writes visible
        float z = 0.f;
        if (wv < 2) z = hist[b_elem * (T_HIST * 2) + (t + 1) * 2 + wv];
        stack(0, parity);
        if (wv < 2) {
            kpred(ge0 * ge0, ge0 * ge1, ge0 * ge2, ge1 * ge1, ge1 * ge2, ge2 * ge2);
            float y = z - X0;
            float Sinv = 1.0f / (P00 + Rch);
            float K0 = P00 * Sinv, K1 = P01 * Sinv, K2 = P02 * Sinv;
            X0 += y * K0; X1 += y * K1; X2 += y * K2;
            float p00 = P00, p01 = P01, p02 = P02;
            P00 = p00 - K0 * p00;
            P01 = p01 - K0 * p01;
            P02 = p02 - K0 * p02;
            P11 = P11 - K1 * p01;
            P12 = P12 - K1 * p02;
            P22 = P22 - K2 * p02;
            write_xp();
        }
        parity ^= 1;
    }

    // ---------------- decoder: 30 steps ----------------
    for (int t = 0; t < LEN_PRED; ++t) {
        __syncthreads();
        stack(1, parity);
        if (wv < 2) {
            // pred = c2 @ Wout^T + b; rows 0..3 live on q==0 lanes
            bfrag8 bc2 = *(const bfrag8*)&xin[3][m][q * 8];
            f32x4 ap = __builtin_amdgcn_mfma_f32_16x16x32_bf16(woutF, bc2, zero4, 0, 0, 0);
            float pe = (wv == 0) ? (ap[0] + woutB[0]) : (ap[1] + woutB[1]);
            float qe = (wv == 0) ? (ap[2] + woutB[2]) : (ap[3] + woutB[3]);
            X2 = DT * pe;
            float qs = qe * qe;
            kpred(qs * g0 * g0, qs * g0 * g1, qs * g0 * g2, qs * g1 * g1, qs * g1 * g2, qs * g2 * g2);
            if (q == 0) {
                float* o = out + (size_t)b_elem * (LEN_PRED * 5) + t * 5;
                if (wv == 0) { o[0] = X0; o[2] = sqrtf(P00); }
                else         { o[1] = X0; o[3] = sqrtf(P00); o[4] = 0.f; }
            }
            write_xp();
        }
        parity ^= 1;
    }
}

extern "C" void kernel_launch(void* const* d_in, const int* in_sizes, int n_in,
                              void* d_out, int out_size, void* d_ws, size_t ws_size,
                              hipStream_t stream)
{
    const float* hist  = (const float*)d_in[0];
    const float* maxax = (const float*)d_in[1];
    const float* maxay = (const float*)d_in[2];
    const float* vstd  = (const float*)d_in[3];
    const float* astd  = (const float*)d_in[4];
    const float* Rx    = (const float*)d_in[5];
    const float* Ry    = (const float*)d_in[6];
    const float* Gx    = (const float*)d_in[7];
    const float* Gy    = (const float*)d_in[8];
    const float* WinW  = (const float*)d_in[9];
    const float* Winb  = (const float*)d_in[10];
    const float* eWih  = (const float*)d_in[11];
    const float* eWhh  = (const float*)d_in[12];
    const float* ebih  = (const float*)d_in[13];
    const float* ebhh  = (const float*)d_in[14];
    const float* dWih  = (const float*)d_in[15];
    const float* dWhh  = (const float*)d_in[16];
    const float* dbih  = (const float*)d_in[17];
    const float* dbhh  = (const float*)d_in[18];
    const float* WoutW = (const float*)d_in[19];
    const float* Woutb = (const float*)d_in[20];
    float* out = (float*)d_out;

    kalman_lstm_kernel<<<512, 256, 0, stream>>>(hist, maxax, maxay, vstd, astd,
                                                Rx, Ry, Gx, Gy,
                                                WinW, Winb, eWih, eWhh, ebih, ebhh,
                                                dWih, dWhh, dbih, dbhh, WoutW, Woutb,
                                                out);
}

// Round 3
// 193.885 us; speedup vs baseline: 1.5664x; 1.5664x over previous
//
#include <hip/hip_runtime.h>
#include <math.h>

#define DT   0.1f
#define HDT  0.005f
#define T_HIST 20
#define LEN_PRED 30

typedef __attribute__((ext_vector_type(8))) short bfrag8;   // 8 bf16 = 4 VGPRs
typedef __attribute__((ext_vector_type(4))) short short4v;  // 8 bytes
typedef __attribute__((ext_vector_type(4))) float f32x4;

// d_ws layout (bytes)
#define WS_FRAG   0u        // 96 frags * 512 bf16 * 2B = 98304
#define WS_WIN    98304u    // 2 frags * 1024B
#define WS_WOUT   100352u   // 1 frag * 1024B
#define WS_BIAS   101376u   // 2*3*128 floats = 3072B

static __device__ __forceinline__ unsigned short f2bf(float x) {
    union { float f; unsigned int u; } v; v.f = x;
    unsigned int r = v.u + 0x7fffu + ((v.u >> 16) & 1u);   // RNE
    return (unsigned short)(r >> 16);
}

// ---------------- weight prep: swizzle into row-permuted MFMA A-frag order ----------------
// Layer frag (ph,l,wv,j,c): tile-row p (=lane&15) maps to W row (p&3)*32 + wv*8 + 4*j + (p>>2)
// so each D-lane gets all 4 gates of one feature.
__global__ void prep_kernel(const float* __restrict__ Win_W,
                            const float* __restrict__ eWih, const float* __restrict__ eWhh,
                            const float* __restrict__ ebih, const float* __restrict__ ebhh,
                            const float* __restrict__ dWih, const float* __restrict__ dWhh,
                            const float* __restrict__ dbih, const float* __restrict__ dbhh,
                            const float* __restrict__ Wout_W,
                            char* __restrict__ ws)
{
    int i = blockIdx.x * blockDim.x + threadIdx.x;
    if (i < 49152) {
        int fi = i >> 9, within = i & 511;
        int lane = within >> 3, jj = within & 7;
        int c = fi & 1, j = (fi >> 1) & 1, wvv = (fi >> 2) & 3;
        int pl = fi >> 4;                 // ph*3 + l
        int l = pl % 3, ph = pl / 3;
        int m = lane & 15, q2 = lane >> 4;
        int gate = m & 3;
        int feat = wvv * 8 + 4 * j + (m >> 2);
        int row = gate * 32 + feat;
        int k = q2 * 8 + jj;
        const float* W = (c == 0) ? (ph ? dWih : eWih) : (ph ? dWhh : eWhh);
        ((unsigned short*)(ws + WS_FRAG))[i] = f2bf(W[l * 4096 + row * 32 + k]);
    } else if (i < 50176) {
        int i2 = i - 49152;
        int w = i2 >> 9, within = i2 & 511;
        int lane = within >> 3, jj = within & 7;
        int m = lane & 15, q2 = lane >> 4;
        int k = q2 * 8 + jj;
        float v = (k < 24) ? Win_W[(w * 16 + m) * 24 + k] : 0.f;
        ((unsigned short*)(ws + WS_WIN))[i2] = f2bf(v);
    } else if (i < 50688) {
        int i3 = i - 50176;
        int lane = i3 >> 3, jj = i3 & 7;
        int m = lane & 15, q2 = lane >> 4;
        float v = (m < 4) ? Wout_W[m * 32 + q2 * 8 + jj] : 0.f;
        ((unsigned short*)(ws + WS_WOUT))[i3] = f2bf(v);
    } else if (i < 51456) {
        int b = i - 50688;                 // combined biases bih+bhh
        int ph = b / 384, rem = b % 384;
        int l = rem >> 7, row = rem & 127;
        const float* bi = ph ? dbih : ebih;
        const float* bh = ph ? dbhh : ebhh;
        ((float*)(ws + WS_BIAS))[b] = bi[l * 128 + row] + bh[l * 128 + row];
    }
}

// ---------------- main kernel: 16 elems / 4-wave block, 2 c-updates per lane ----------------
__launch_bounds__(256, 2)
__global__ void kalman_lstm_kernel(const float* __restrict__ hist,
                                   const float* __restrict__ max_ax, const float* __restrict__ max_ay,
                                   const float* __restrict__ vstd, const float* __restrict__ astd,
                                   const float* __restrict__ Rx_, const float* __restrict__ Ry_,
                                   const float* __restrict__ Gx, const float* __restrict__ Gy,
                                   const float* __restrict__ Win_b, const float* __restrict__ Wout_b,
                                   const char* __restrict__ ws, float* __restrict__ out)
{
    __shared__ __align__(16) unsigned short xin[4][16][40];     // layer inputs (x0, c0, c1, c2)
    __shared__ __align__(16) unsigned short hbuf[2][3][16][40]; // double-buffered h
    __shared__ __align__(16) unsigned short xpw[2][16][40];     // private XP per Kalman wave

    const int tid  = threadIdx.x;
    const int wv   = tid >> 6;        // 0..3; waves 2,3 also run Kalman/Win/Wout
    const int lane = tid & 63;
    const int q    = lane >> 4;
    const int m    = lane & 15;       // elem index
    const int b_elem = blockIdx.x * 16 + m;

    // ---- per-phase layer weights in registers (12 frags = 48 VGPRs) ----
    bfrag8 fragA[3][2][2];
    float  biasR[3][2][4];
    const bfrag8* fragp = (const bfrag8*)(ws + WS_FRAG);
    const float*  combp = (const float*)(ws + WS_BIAS);
    auto load_phase = [&](int ph) {
#pragma unroll
        for (int l = 0; l < 3; ++l)
#pragma unroll
            for (int j = 0; j < 2; ++j) {
#pragma unroll
                for (int c = 0; c < 2; ++c) {
                    int fi = (((ph * 3 + l) * 4 + wv) * 2 + j) * 2 + c;
                    fragA[l][j][c] = fragp[fi * 64 + lane];
                }
#pragma unroll
                for (int r = 0; r < 4; ++r)
                    biasR[l][j][r] = combp[ph * 384 + l * 128 + r * 32 + (wv * 8 + 4 * j + q)];
            }
    };
    load_phase(0);

    // ---- Kalman-wave state (waves 2,3; each lane: channel ch = q&1) ----
    bfrag8 winF = {}, woutF = {};
    f32x4 winB = {0.f, 0.f, 0.f, 0.f};
    float wb0 = 0.f, wb1 = 0.f, wb2 = 0.f, wb3 = 0.f;
    float g0 = 0.f, g1 = 0.f, g2 = 0.f, ge0 = 0.f, ge1 = 0.f, ge2 = 0.f;
    float Rch = 0.f, X0 = 0.f, X1 = 0.f, X2 = 0.f;
    float P00 = 0.f, P01 = 0.f, P02 = 0.f, P11 = 0.f, P12 = 0.f, P22 = 0.f;
    const int ch = q & 1;
    if (wv >= 2) {
        int w = wv - 2;
        winF  = ((const bfrag8*)(ws + WS_WIN))[w * 64 + lane];
        woutF = ((const bfrag8*)(ws + WS_WOUT))[lane];
#pragma unroll
        for (int r = 0; r < 4; ++r) winB[r] = Win_b[w * 16 + q * 4 + r];
        wb0 = Wout_b[0]; wb1 = Wout_b[1]; wb2 = Wout_b[2]; wb3 = Wout_b[3];
        const float rx = Rx_[0] * Rx_[0], ry = Ry_[0] * Ry_[0];
        Rch = ch ? ry : rx;
        if (ch == 0) { g0 = Gx[0]; g1 = Gx[1]; g2 = Gx[2]; float s = max_ax[0]; ge0 = g0*s; ge1 = g1*s; ge2 = g2*s; }
        else         { g0 = Gy[0]; g1 = Gy[1]; g2 = Gy[2]; float s = max_ay[0]; ge0 = g0*s; ge1 = g1*s; ge2 = g2*s; }
        X0 = hist[b_elem * (T_HIST * 2) + ch];
        P00 = Rch; P11 = vstd[0] * vstd[0]; P22 = astd[0] * astd[0];
    }

    float creg[3][2];
#pragma unroll
    for (int l = 0; l < 3; ++l) { creg[l][0] = 0.f; creg[l][1] = 0.f; }

    // ---- LDS zero init ----
    for (int idx = tid; idx < 4 * 16 * 40; idx += 256) (&xin[0][0][0])[idx] = 0;
    for (int idx = tid; idx < 2 * 3 * 16 * 40; idx += 256) (&hbuf[0][0][0][0])[idx] = 0;
    for (int idx = tid; idx < 2 * 16 * 40; idx += 256) (&xpw[0][0][0])[idx] = 0;

    auto sig = [](float z) { return __builtin_amdgcn_rcpf(1.f + __expf(-z)); };
    auto th  = [](float z) { return fmaf(-2.f, __builtin_amdgcn_rcpf(__expf(2.f * z) + 1.f), 1.f); };

    auto kpred = [&](float Q00, float Q01, float Q02, float Q11, float Q12, float Q22) {
        X0 = X0 + DT * X1 + HDT * X2;
        X1 = X1 + DT * X2;
        float M00 = P00 + DT * P01 + HDT * P02;
        float M01 = P01 + DT * P11 + HDT * P12;
        float M02 = P02 + DT * P12 + HDT * P22;
        float M11 = P11 + DT * P12;
        float M12 = P12 + DT * P22;
        float M22 = P22;
        P00 = M00 + DT * M01 + HDT * M02 + Q00;
        P01 = M01 + DT * M02 + Q01;
        P02 = M02 + Q02;
        P11 = M11 + DT * M12 + Q11;
        P12 = M12 + Q12;
        P22 = M22 + Q22;
    };
    auto kupdate = [&](float z) {
        float y = z - X0;
        float Sinv = 1.0f / (P00 + Rch);
        float K0 = P00 * Sinv, K1 = P01 * Sinv, K2 = P02 * Sinv;
        X0 += y * K0; X1 += y * K1; X2 += y * K2;
        float p00 = P00, p01 = P01, p02 = P02;
        P00 = p00 - K0 * p00;
        P01 = p01 - K0 * p01;
        P02 = p02 - K0 * p02;
        P11 = P11 - K1 * p01;
        P12 = P12 - K1 * p02;
        P22 = P22 - K2 * p02;
    };
    auto write_xp = [&]() {       // q0 lanes write x-cols, q1 lanes y-cols (private copy)
        if (q < 2) {
            unsigned short* row = &xpw[wv - 2][m][0];
            int o = ch * 3;
            row[o + 0] = f2bf(X0); row[o + 1] = f2bf(X1); row[o + 2] = f2bf(X2);
            int pb = 6 + ch * 9;
            row[pb + 0] = f2bf(P00); row[pb + 1] = f2bf(P01); row[pb + 2] = f2bf(P02);
            row[pb + 3] = f2bf(P01); row[pb + 4] = f2bf(P11); row[pb + 5] = f2bf(P12);
            row[pb + 6] = f2bf(P02); row[pb + 7] = f2bf(P12); row[pb + 8] = f2bf(P22);
        }
    };

    const f32x4 zero4 = {0.f, 0.f, 0.f, 0.f};

    // region A: waves 2,3 advance Kalman (mode 0: encoder z-update; mode 1: decoder Wout->pred),
    // write private XP, run Win MFMA -> xin0. Waves 0,1 idle (other block's waves fill the SIMD).
    auto regionA = [&](int mode, int t) {
        if (wv >= 2) {
            if (mode == 0) {
                if (t > 0) {
                    float z = hist[b_elem * (T_HIST * 2) + t * 2 + ch];
                    kpred(ge0 * ge0, ge0 * ge1, ge0 * ge2, ge1 * ge1, ge1 * ge2, ge2 * ge2);
                    kupdate(z);
                }
            } else {
                if (t == 0) {      // finish encoder step 18 with z_19
                    float z = hist[b_elem * (T_HIST * 2) + 19 * 2 + ch];
                    kpred(ge0 * ge0, ge0 * ge1, ge0 * ge2, ge1 * ge1, ge1 * ge2, ge2 * ge2);
                    kupdate(z);
                } else {           // process decoder step t-1: pred from c2, out store
                    bfrag8 bc2 = *(const bfrag8*)&xin[3][m][q * 8];
                    f32x4 ap = __builtin_amdgcn_mfma_f32_16x16x32_bf16(woutF, bc2, zero4, 0, 0, 0);
                    float a0 = ap[0] + wb0, a1 = ap[1] + wb1, a2 = ap[2] + wb2, a3 = ap[3] + wb3;
                    float s0 = __shfl(a0, m), s1 = __shfl(a1, m);
                    float s2 = __shfl(a2, m), s3 = __shfl(a3, m);
                    float pe = ch ? s1 : s0;
                    float qe = ch ? s3 : s2;
                    X2 = DT * pe;
                    float qs = qe * qe;
                    kpred(qs*g0*g0, qs*g0*g1, qs*g0*g2, qs*g1*g1, qs*g1*g2, qs*g2*g2);
                    if (wv == 2 && q < 2) {
                        float* o = out + (size_t)b_elem * (LEN_PRED * 5) + (t - 1) * 5;
                        if (ch == 0) { o[0] = X0; o[2] = sqrtf(P00); }
                        else         { o[1] = X0; o[3] = sqrtf(P00); o[4] = 0.f; }
                    }
                }
            }
            write_xp();
            // Win: wave wv covers feats (wv-2)*16 .. +15, reads own private XP
            bfrag8 bxp = *(const bfrag8*)&xpw[wv - 2][m][q * 8];
            f32x4 aw = __builtin_amdgcn_mfma_f32_16x16x32_bf16(winF, bxp, zero4, 0, 0, 0);
            union { short4v v; unsigned short s[4]; } u;
#pragma unroll
            for (int r = 0; r < 4; ++r) u.s[r] = f2bf(th(aw[r] + winB[r]));
            *(short4v*)&xin[0][m][(wv - 2) * 16 + q * 4] = u.v;
        }
        __syncthreads();
    };

    auto layers = [&](int p) {
#pragma unroll
        for (int l = 0; l < 3; ++l) {
            bfrag8 bx = *(const bfrag8*)&xin[l][m][q * 8];
            bfrag8 bh = *(const bfrag8*)&hbuf[p][l][m][q * 8];
            f32x4 a0 = __builtin_amdgcn_mfma_f32_16x16x32_bf16(fragA[l][0][0], bx, zero4, 0, 0, 0);
            a0        = __builtin_amdgcn_mfma_f32_16x16x32_bf16(fragA[l][0][1], bh, a0, 0, 0, 0);
            f32x4 a1 = __builtin_amdgcn_mfma_f32_16x16x32_bf16(fragA[l][1][0], bx, zero4, 0, 0, 0);
            a1        = __builtin_amdgcn_mfma_f32_16x16x32_bf16(fragA[l][1][1], bh, a1, 0, 0, 0);
#pragma unroll
            for (int j = 0; j < 2; ++j) {
                f32x4 a = j ? a1 : a0;
                float iv = sig(a[0] + biasR[l][j][0]);
                float fv = sig(a[1] + biasR[l][j][1]);
                float gv = th (a[2] + biasR[l][j][2]);
                float ov = sig(a[3] + biasR[l][j][3]);
                float cn = fmaf(fv, creg[l][j], iv * gv);
                float hn = ov * th(cn);
                creg[l][j] = cn;
                int f = wv * 8 + 4 * j + q;
                xin[l + 1][m][f] = f2bf(cn);
                hbuf[p ^ 1][l][m][f] = f2bf(hn);
            }
            __syncthreads();
        }
    };

    __syncthreads();     // LDS zero init visible
    int p = 0;

    for (int t = 0; t < T_HIST - 1; ++t) { regionA(0, t); layers(p); p ^= 1; }
    load_phase(1);
    for (int t = 0; t < LEN_PRED; ++t)   { regionA(1, t); layers(p); p ^= 1; }

    // epilogue: decoder step 29's pred + out (xin[3] stable since last barrier)
    if (wv == 2) {
        bfrag8 bc2 = *(const bfrag8*)&xin[3][m][q * 8];
        f32x4 ap = __builtin_amdgcn_mfma_f32_16x16x32_bf16(woutF, bc2, zero4, 0, 0, 0);
        float a0 = ap[0] + wb0, a1 = ap[1] + wb1, a2 = ap[2] + wb2, a3 = ap[3] + wb3;
        float s0 = __shfl(a0, m), s1 = __shfl(a1, m);
        float s2 = __shfl(a2, m), s3 = __shfl(a3, m);
        float pe = ch ? s1 : s0;
        float qe = ch ? s3 : s2;
        X2 = DT * pe;
        float qs = qe * qe;
        kpred(qs*g0*g0, qs*g0*g1, qs*g0*g2, qs*g1*g1, qs*g1*g2, qs*g2*g2);
        if (q < 2) {
            float* o = out + (size_t)b_elem * (LEN_PRED * 5) + (LEN_PRED - 1) * 5;
            if (ch == 0) { o[0] = X0; o[2] = sqrtf(P00); }
            else         { o[1] = X0; o[3] = sqrtf(P00); o[4] = 0.f; }
        }
    }
}

extern "C" void kernel_launch(void* const* d_in, const int* in_sizes, int n_in,
                              void* d_out, int out_size, void* d_ws, size_t ws_size,
                              hipStream_t stream)
{
    const float* hist  = (const float*)d_in[0];
    const float* maxax = (const float*)d_in[1];
    const float* maxay = (const float*)d_in[2];
    const float* vstd  = (const float*)d_in[3];
    const float* astd  = (const float*)d_in[4];
    const float* Rx    = (const float*)d_in[5];
    const float* Ry    = (const float*)d_in[6];
    const float* Gx    = (const float*)d_in[7];
    const float* Gy    = (const float*)d_in[8];
    const float* WinW  = (const float*)d_in[9];
    const float* Winb  = (const float*)d_in[10];
    const float* eWih  = (const float*)d_in[11];
    const float* eWhh  = (const float*)d_in[12];
    const float* ebih  = (const float*)d_in[13];
    const float* ebhh  = (const float*)d_in[14];
    const float* dWih  = (const float*)d_in[15];
    const float* dWhh  = (const float*)d_in[16];
    const float* dbih  = (const float*)d_in[17];
    const float* dbhh  = (const float*)d_in[18];
    const float* WoutW = (const float*)d_in[19];
    const float* Woutb = (const float*)d_in[20];
    char* ws = (char*)d_ws;
    float* out = (float*)d_out;

    prep_kernel<<<202, 256, 0, stream>>>(WinW, eWih, eWhh, ebih, ebhh,
                                         dWih, dWhh, dbih, dbhh, WoutW, ws);
    kalman_lstm_kernel<<<512, 256, 0, stream>>>(hist, maxax, maxay, vstd, astd,
                                                Rx, Ry, Gx, Gy, Winb, Woutb,
                                                ws, out);
}